// Round 1
// baseline (280.101 us; speedup 1.0000x reference)
//
#include <hip/hip_runtime.h>
#include <hip/hip_bf16.h>
#include <math.h>

// ---- problem constants ----
#define BB     256
#define TT     64
#define BT     (BB*TT)      // 16384 tokens
#define XD     44
#define XP     40
#define XS     10
#define HID    128
#define XEMB   32
#define NHID   8
#define NAG    10
#define NEDGE  90
#define GEMB   720          // NHID*NEDGE
#define KF     768          // padded fused feature dim (763 -> 768)
#define NTOT   640          // 128 (a) + 128 (o) + 384 (ih)

typedef __bf16  bf16_t;
typedef __bf16  bf16x8 __attribute__((ext_vector_type(8)));
typedef float   floatx4 __attribute__((ext_vector_type(4)));

__device__ __forceinline__ float elu_f(float v) { return v > 0.f ? v : expm1f(v); }
__device__ __forceinline__ float sigmoid_f(float v) { return 1.f / (1.f + expf(-v)); }

// ---------------------------------------------------------------------------
// Kernel 1: build Wcat^T (n-major, k-contiguous) bf16 + fused bias (fp32)
// F feature layout: [0:32) xemb | [32:42) demo | [42] treat | [43:763) gemb | [763:768) pad0
// ---------------------------------------------------------------------------
__global__ __launch_bounds__(256) void prep_kernel(
    const float* __restrict__ Wa1, const float* __restrict__ ba1,
    const float* __restrict__ Wo1, const float* __restrict__ bo1,
    const float* __restrict__ Wih, const float* __restrict__ bih,
    bf16_t* __restrict__ WT, float* __restrict__ bcat) {
  int idx = blockIdx.x * 256 + threadIdx.x;
  if (idx >= NTOT * KF) return;
  int n = idx / KF, k = idx - n * KF;
  float v = 0.f;
  if (n < 128) {                       // W_a1: a_in = [demo(10), gemb(720)]
    if (k >= 32 && k < 42)        v = Wa1[n * 730 + (k - 32)];
    else if (k >= 43 && k < 763)  v = Wa1[n * 730 + 10 + (k - 43)];
  } else if (n < 256) {                // W_o1: o_in == F[0:763] exactly
    int m = n - 128;
    if (k < 763)                  v = Wo1[m * 763 + k];
  } else {                             // W_ih: rnn_in = [xemb(32), treat(1), gemb(720)]
    int m = n - 256;
    if (k < 32)                   v = Wih[m * 753 + k];
    else if (k == 42)             v = Wih[m * 753 + 32];
    else if (k >= 43 && k < 763)  v = Wih[m * 753 + 33 + (k - 43)];
  }
  WT[n * KF + k] = (bf16_t)v;
  if (k == 0) {
    bcat[n] = (n < 128) ? ba1[n] : (n < 256 ? bo1[n - 128] : bih[n - 256]);
  }
}

// ---------------------------------------------------------------------------
// Kernel 2: per-token graph-net encoder -> F (bf16, 16384 x 768)
// one wave (64 threads) per token
// ---------------------------------------------------------------------------
#define W_M1A 0
#define B_M1A 32
#define W_M1B 40
#define B_M1B 104
#define W_M2A 112
#define B_M2A 240
#define W_M2B 248
#define B_M2B 312
#define W_X2E 320
#define B_X2E 448
#define W_ST  480
#define B_ST  580
#define W_TOT 590

__global__ __launch_bounds__(64) void encoder_kernel(
    const float* __restrict__ x, const float* __restrict__ x_demo,
    const float* __restrict__ ftreat,
    const float* __restrict__ Wm1a, const float* __restrict__ bm1a,
    const float* __restrict__ Wm1b, const float* __restrict__ bm1b,
    const float* __restrict__ Wm2a, const float* __restrict__ bm2a,
    const float* __restrict__ Wm2b, const float* __restrict__ bm2b,
    const float* __restrict__ Wx2e, const float* __restrict__ bx2e,
    const float* __restrict__ Wst, const float* __restrict__ bst,
    bf16_t* __restrict__ F) {
  int tok = blockIdx.x;
  int b = tok >> 6, t = tok & 63;
  int tid = threadIdx.x;

  __shared__ float w[W_TOT];
  __shared__ float xl[XD];
  __shared__ float h1a[NAG * 8];
  __shared__ float h1s[NAG * 8];
  __shared__ float h2a[NEDGE * 8];

  for (int i = tid; i < 32;  i += 64) w[W_M1A + i] = Wm1a[i];
  for (int i = tid; i < 8;   i += 64) w[B_M1A + i] = bm1a[i];
  for (int i = tid; i < 64;  i += 64) w[W_M1B + i] = Wm1b[i];
  for (int i = tid; i < 8;   i += 64) w[B_M1B + i] = bm1b[i];
  for (int i = tid; i < 128; i += 64) w[W_M2A + i] = Wm2a[i];
  for (int i = tid; i < 8;   i += 64) w[B_M2A + i] = bm2a[i];
  for (int i = tid; i < 64;  i += 64) w[W_M2B + i] = Wm2b[i];
  for (int i = tid; i < 8;   i += 64) w[B_M2B + i] = bm2b[i];
  for (int i = tid; i < 128; i += 64) w[W_X2E + i] = Wx2e[i];
  for (int i = tid; i < 32;  i += 64) w[B_X2E + i] = bx2e[i];
  for (int i = tid; i < 100; i += 64) w[W_ST + i]  = Wst[i];
  for (int i = tid; i < 10;  i += 64) w[B_ST + i]  = bst[i];
  if (tid < XD) xl[tid] = x[(size_t)(b * 65 + t) * XD + tid];
  __syncthreads();

  // h1a = elu(xa @ Wm1a^T + b)
  for (int c = tid; c < NAG * 8; c += 64) {
    int i = c >> 3, o = c & 7;
    float s = w[B_M1A + o];
#pragma unroll
    for (int f = 0; f < 4; f++) s += xl[i * 4 + f] * w[W_M1A + o * 4 + f];
    h1a[c] = elu_f(s);
  }
  __syncthreads();
  // h1 = elu(h1a @ Wm1b^T + b)
  for (int c = tid; c < NAG * 8; c += 64) {
    int i = c >> 3, o = c & 7;
    float s = w[B_M1B + o];
#pragma unroll
    for (int p = 0; p < 8; p++) s += h1a[i * 8 + p] * w[W_M1B + o * 8 + p];
    h1s[c] = elu_f(s);
  }
  __syncthreads();
  // h2a = elu(edges @ Wm2a^T + b)  (edge e: recv=e/9, send=q+(q>=r))
  for (int c = tid; c < NEDGE * 8; c += 64) {
    int e = c >> 3, o = c & 7;
    int r = e / 9, q = e - 9 * r;
    int sd = q + (q >= r ? 1 : 0);
    float s = w[B_M2A + o];
#pragma unroll
    for (int kk = 0; kk < 8; kk++) s += h1s[r * 8 + kk]  * w[W_M2A + o * 16 + kk];
#pragma unroll
    for (int kk = 0; kk < 8; kk++) s += h1s[sd * 8 + kk] * w[W_M2A + o * 16 + 8 + kk];
    h2a[c] = elu_f(s);
  }
  __syncthreads();

  bf16_t* Frow = F + (size_t)tok * KF;
  // gemb = elu(h2a @ Wm2b^T + b) -> F[43:763)
  for (int c = tid; c < NEDGE * 8; c += 64) {
    int e = c >> 3, o = c & 7;
    float s = w[B_M2B + o];
#pragma unroll
    for (int kk = 0; kk < 8; kk++) s += h2a[e * 8 + kk] * w[W_M2B + o * 8 + kk];
    Frow[43 + c] = (bf16_t)elu_f(s);
  }
  // xemb -> F[0:32)
  if (tid < 32) {
    float s = w[B_X2E + tid];
#pragma unroll
    for (int f = 0; f < 4; f++) s += xl[40 + f] * w[W_X2E + tid * 4 + f];
    Frow[tid] = (bf16_t)s;
  } else if (tid < 42) {               // demo -> F[32:42)
    int d = tid - 32;
    float s = w[B_ST + d];
#pragma unroll
    for (int j = 0; j < 10; j++) s += x_demo[b * XS + j] * w[W_ST + d * 10 + j];
    Frow[tid] = (bf16_t)s;
  } else if (tid == 42) {              // treat -> F[42]
    Frow[42] = (bf16_t)ftreat[b * 65 + t];
  } else if (tid < 48) {               // pad -> F[763:768) = 0
    Frow[720 + tid] = (bf16_t)0.f;
  }
}

// ---------------------------------------------------------------------------
// Kernel 3: G[16384,640] = F[16384,768] @ WT^T + bcat  (bf16 MFMA, fp32 acc)
// 128x128 block tile, 4 waves each 64x64, 16x16x32 bf16, BK=32
// ---------------------------------------------------------------------------
__global__ __launch_bounds__(256) void gemm_kernel(
    const bf16_t* __restrict__ F, const bf16_t* __restrict__ WT,
    const float* __restrict__ bcat, float* __restrict__ G) {
  __shared__ __align__(16) bf16_t As[128 * 32];
  __shared__ __align__(16) bf16_t Bs[128 * 32];

  int tid  = threadIdx.x;
  int lane = tid & 63;
  int wv   = tid >> 6;
  int wr   = wv >> 1, wc = wv & 1;
  int m0 = blockIdx.x * 128, n0 = blockIdx.y * 128;

  floatx4 acc[4][4];
#pragma unroll
  for (int i = 0; i < 4; i++)
#pragma unroll
    for (int j = 0; j < 4; j++) acc[i][j] = floatx4{0.f, 0.f, 0.f, 0.f};

  int c0 = tid, c1 = tid + 256;          // 16B chunks: row=c>>2, kp=c&3
  int r0 = c0 >> 2, p0 = c0 & 3;
  int r1 = c1 >> 2, p1 = c1 & 3;
  int qr = lane >> 4;                    // k-quad
  int lr = lane & 15;                    // m/n within tile

  for (int k0 = 0; k0 < KF; k0 += 32) {
    uint4 a0 = *(const uint4*)(F  + (size_t)(m0 + r0) * KF + k0 + p0 * 8);
    uint4 a1 = *(const uint4*)(F  + (size_t)(m0 + r1) * KF + k0 + p1 * 8);
    uint4 b0 = *(const uint4*)(WT + (size_t)(n0 + r0) * KF + k0 + p0 * 8);
    uint4 b1 = *(const uint4*)(WT + (size_t)(n0 + r1) * KF + k0 + p1 * 8);
    __syncthreads();
    ((uint4*)As)[c0] = a0; ((uint4*)As)[c1] = a1;
    ((uint4*)Bs)[c0] = b0; ((uint4*)Bs)[c1] = b1;
    __syncthreads();

    bf16x8 af[4], bf[4];
#pragma unroll
    for (int i = 0; i < 4; i++) {
      af[i] = *(const bf16x8*)(As + (wr * 64 + i * 16 + lr) * 32 + qr * 8);
      bf[i] = *(const bf16x8*)(Bs + (wc * 64 + i * 16 + lr) * 32 + qr * 8);
    }
#pragma unroll
    for (int i = 0; i < 4; i++)
#pragma unroll
      for (int j = 0; j < 4; j++)
        acc[i][j] = __builtin_amdgcn_mfma_f32_16x16x32_bf16(af[i], bf[j], acc[i][j], 0, 0, 0);
  }

  // epilogue: add bias, store fp32. C/D map: col=lane&15, row=(lane>>4)*4+reg
#pragma unroll
  for (int i = 0; i < 4; i++) {
#pragma unroll
    for (int j = 0; j < 4; j++) {
      int col = n0 + wc * 64 + j * 16 + lr;
      float bv = bcat[col];
#pragma unroll
      for (int r = 0; r < 4; r++) {
        int row = m0 + wr * 64 + i * 16 + qr * 4 + r;
        G[(size_t)row * NTOT + col] = acc[i][j][r] + bv;
      }
    }
  }
}

// ---------------------------------------------------------------------------
// Kernel 4: heads — a_out / y_out (one wave per token)
// ---------------------------------------------------------------------------
__global__ __launch_bounds__(256) void head_kernel(
    const float* __restrict__ G, const float* __restrict__ Wa2,
    const float* __restrict__ Wo2, float* __restrict__ out) {
  int wid  = (blockIdx.x * 256 + threadIdx.x) >> 6;   // token
  int lane = threadIdx.x & 63;
  const float* g = G + (size_t)wid * NTOT;
  float sa = fmaxf(g[lane], 0.f) * Wa2[lane] + fmaxf(g[lane + 64], 0.f) * Wa2[lane + 64];
  float sy = fmaxf(g[128 + lane], 0.f) * Wo2[lane] + fmaxf(g[192 + lane], 0.f) * Wo2[lane + 64];
#pragma unroll
  for (int off = 32; off > 0; off >>= 1) {
    sa += __shfl_down(sa, off, 64);
    sy += __shfl_down(sy, off, 64);
  }
  if (lane == 0) {
    out[(size_t)wid * 130 + 0] = sa;
    out[(size_t)wid * 130 + 1] = sy;
  }
}

// ---------------------------------------------------------------------------
// Kernel 5: GRU — one block per sequence, thread j owns W_hh row j in VGPRs
// ---------------------------------------------------------------------------
__global__ __launch_bounds__(384, 1) void gru_kernel(
    const float* __restrict__ G, const float* __restrict__ h0,
    const float* __restrict__ Whh, const float* __restrict__ bhh,
    float* __restrict__ out) {
  int b = blockIdx.x;
  int tid = threadIdx.x;

  __shared__ float hbuf[2][HID];
  __shared__ float gh[384];

  float wrow[HID];
#pragma unroll
  for (int k = 0; k < HID; k += 4) {
    float4 v = *(const float4*)(Whh + (size_t)tid * HID + k);
    wrow[k] = v.x; wrow[k + 1] = v.y; wrow[k + 2] = v.z; wrow[k + 3] = v.w;
  }
  float bias = bhh[tid];
  if (tid < HID) hbuf[0][tid] = h0[(size_t)b * HID + tid];
  __syncthreads();

  int cur = 0;
  for (int t = 0; t < TT; t++) {
    float s = 0.f;
#pragma unroll
    for (int k = 0; k < HID; k += 4) {
      float4 h4 = *(const float4*)(&hbuf[cur][k]);
      s += wrow[k] * h4.x + wrow[k + 1] * h4.y + wrow[k + 2] * h4.z + wrow[k + 3] * h4.w;
    }
    gh[tid] = s + bias;
    __syncthreads();
    if (tid < HID) {
      const float* grow = G + (size_t)(b * TT + t) * NTOT;
      float ir = grow[256 + tid], iz = grow[384 + tid], inn = grow[512 + tid];
      float r = sigmoid_f(ir + gh[tid]);
      float z = sigmoid_f(iz + gh[128 + tid]);
      float n = tanhf(inn + r * gh[256 + tid]);
      float hn = (1.f - z) * n + z * hbuf[cur][tid];
      hbuf[cur ^ 1][tid] = hn;
      out[(size_t)(b * TT + t) * 130 + 2 + tid] = hn;
    }
    __syncthreads();
    cur ^= 1;
  }
}

// ---------------------------------------------------------------------------
extern "C" void kernel_launch(void* const* d_in, const int* in_sizes, int n_in,
                              void* d_out, int out_size, void* d_ws, size_t ws_size,
                              hipStream_t stream) {
  const float* x      = (const float*)d_in[0];
  const float* x_demo = (const float*)d_in[1];
  const float* ftr    = (const float*)d_in[2];
  const float* h0     = (const float*)d_in[3];
  const float* Wx2e   = (const float*)d_in[4];
  const float* bx2e   = (const float*)d_in[5];
  const float* Wst    = (const float*)d_in[6];
  const float* bst    = (const float*)d_in[7];
  const float* Wm1a   = (const float*)d_in[8];
  const float* bm1a   = (const float*)d_in[9];
  const float* Wm1b   = (const float*)d_in[10];
  const float* bm1b   = (const float*)d_in[11];
  const float* Wm2a   = (const float*)d_in[12];
  const float* bm2a   = (const float*)d_in[13];
  const float* Wm2b   = (const float*)d_in[14];
  const float* bm2b   = (const float*)d_in[15];
  const float* Wa1    = (const float*)d_in[16];
  const float* ba1    = (const float*)d_in[17];
  const float* Wa2    = (const float*)d_in[18];
  const float* Wo1    = (const float*)d_in[19];
  const float* bo1    = (const float*)d_in[20];
  const float* Wo2    = (const float*)d_in[21];
  const float* Wih    = (const float*)d_in[22];
  const float* bih    = (const float*)d_in[23];
  const float* Whh    = (const float*)d_in[24];
  const float* bhh    = (const float*)d_in[25];
  float* out = (float*)d_out;

  char* ws = (char*)d_ws;
  bf16_t* F   = (bf16_t*)(ws);                             // 16384*768*2 = 25165824
  bf16_t* WT  = (bf16_t*)(ws + 25165824);                  // 640*768*2   = 983040
  float*  bc  = (float*)(ws + 25165824 + 983040);          // 640*4       = 2560
  float*  G   = (float*)(ws + 25165824 + 983040 + 2560);   // 16384*640*4 = 41943040

  prep_kernel<<<dim3((NTOT * KF + 255) / 256), dim3(256), 0, stream>>>(
      Wa1, ba1, Wo1, bo1, Wih, bih, WT, bc);
  encoder_kernel<<<dim3(BT), dim3(64), 0, stream>>>(
      x, x_demo, ftr, Wm1a, bm1a, Wm1b, bm1b, Wm2a, bm2a, Wm2b, bm2b,
      Wx2e, bx2e, Wst, bst, F);
  gemm_kernel<<<dim3(BT / 128, NTOT / 128), dim3(256), 0, stream>>>(F, WT, bc, G);
  head_kernel<<<dim3(BT / 4), dim3(256), 0, stream>>>(G, Wa2, Wo2, out);
  gru_kernel<<<dim3(BB), dim3(384), 0, stream>>>(G, h0, Whh, bhh, out);
}

// Round 2
// 263.633 us; speedup vs baseline: 1.0625x; 1.0625x over previous
//
#include <hip/hip_runtime.h>
#include <hip/hip_bf16.h>
#include <math.h>

// ---- problem constants ----
#define BB     256
#define TT     64
#define BT     (BB*TT)      // 16384 tokens
#define XD     44
#define XP     40
#define XS     10
#define HID    128
#define XEMB   32
#define NHID   8
#define NAG    10
#define NEDGE  90
#define GEMB   720          // NHID*NEDGE
#define KF     768          // padded fused feature dim (763 -> 768)
#define NTOT   640          // 128 (a) + 128 (o) + 384 (ih)

typedef __bf16  bf16_t;
typedef __bf16  bf16x8 __attribute__((ext_vector_type(8)));
typedef float   floatx4 __attribute__((ext_vector_type(4)));

__device__ __forceinline__ float elu_f(float v) { return v > 0.f ? v : expm1f(v); }
__device__ __forceinline__ float rcp_fast(float x) { return __builtin_amdgcn_rcpf(x); }
__device__ __forceinline__ float sigmoid_fast(float v) { return rcp_fast(1.f + __expf(-v)); }
// inf-safe fast tanh: x->+inf => 1, x->-inf => -1
__device__ __forceinline__ float tanh_fast(float x) { return 1.f - 2.f * rcp_fast(1.f + __expf(2.f * x)); }

// ---------------------------------------------------------------------------
// Kernel 1: build Wcat^T (n-major, k-contiguous) bf16 + fused bias (fp32)
// F feature layout: [0:32) xemb | [32:42) demo | [42] treat | [43:763) gemb | [763:768) pad0
// ---------------------------------------------------------------------------
__global__ __launch_bounds__(256) void prep_kernel(
    const float* __restrict__ Wa1, const float* __restrict__ ba1,
    const float* __restrict__ Wo1, const float* __restrict__ bo1,
    const float* __restrict__ Wih, const float* __restrict__ bih,
    bf16_t* __restrict__ WT, float* __restrict__ bcat) {
  int idx = blockIdx.x * 256 + threadIdx.x;
  if (idx >= NTOT * KF) return;
  int n = idx / KF, k = idx - n * KF;
  float v = 0.f;
  if (n < 128) {                       // W_a1: a_in = [demo(10), gemb(720)]
    if (k >= 32 && k < 42)        v = Wa1[n * 730 + (k - 32)];
    else if (k >= 43 && k < 763)  v = Wa1[n * 730 + 10 + (k - 43)];
  } else if (n < 256) {                // W_o1: o_in == F[0:763] exactly
    int m = n - 128;
    if (k < 763)                  v = Wo1[m * 763 + k];
  } else {                             // W_ih: rnn_in = [xemb(32), treat(1), gemb(720)]
    int m = n - 256;
    if (k < 32)                   v = Wih[m * 753 + k];
    else if (k == 42)             v = Wih[m * 753 + 32];
    else if (k >= 43 && k < 763)  v = Wih[m * 753 + 33 + (k - 43)];
  }
  WT[n * KF + k] = (bf16_t)v;
  if (k == 0) {
    bcat[n] = (n < 128) ? ba1[n] : (n < 256 ? bo1[n - 128] : bih[n - 256]);
  }
}

// ---------------------------------------------------------------------------
// Kernel 2: per-token graph-net encoder -> F (bf16, 16384 x 768)
// one wave (64 threads) per token
// ---------------------------------------------------------------------------
#define W_M1A 0
#define B_M1A 32
#define W_M1B 40
#define B_M1B 104
#define W_M2A 112
#define B_M2A 240
#define W_M2B 248
#define B_M2B 312
#define W_X2E 320
#define B_X2E 448
#define W_ST  480
#define B_ST  580
#define W_TOT 590

__global__ __launch_bounds__(64) void encoder_kernel(
    const float* __restrict__ x, const float* __restrict__ x_demo,
    const float* __restrict__ ftreat,
    const float* __restrict__ Wm1a, const float* __restrict__ bm1a,
    const float* __restrict__ Wm1b, const float* __restrict__ bm1b,
    const float* __restrict__ Wm2a, const float* __restrict__ bm2a,
    const float* __restrict__ Wm2b, const float* __restrict__ bm2b,
    const float* __restrict__ Wx2e, const float* __restrict__ bx2e,
    const float* __restrict__ Wst, const float* __restrict__ bst,
    bf16_t* __restrict__ F) {
  int tok = blockIdx.x;
  int b = tok >> 6, t = tok & 63;
  int tid = threadIdx.x;

  __shared__ float w[W_TOT];
  __shared__ float xl[XD];
  __shared__ float h1a[NAG * 8];
  __shared__ float h1s[NAG * 8];
  __shared__ float h2a[NEDGE * 8];

  for (int i = tid; i < 32;  i += 64) w[W_M1A + i] = Wm1a[i];
  for (int i = tid; i < 8;   i += 64) w[B_M1A + i] = bm1a[i];
  for (int i = tid; i < 64;  i += 64) w[W_M1B + i] = Wm1b[i];
  for (int i = tid; i < 8;   i += 64) w[B_M1B + i] = bm1b[i];
  for (int i = tid; i < 128; i += 64) w[W_M2A + i] = Wm2a[i];
  for (int i = tid; i < 8;   i += 64) w[B_M2A + i] = bm2a[i];
  for (int i = tid; i < 64;  i += 64) w[W_M2B + i] = Wm2b[i];
  for (int i = tid; i < 8;   i += 64) w[B_M2B + i] = bm2b[i];
  for (int i = tid; i < 128; i += 64) w[W_X2E + i] = Wx2e[i];
  for (int i = tid; i < 32;  i += 64) w[B_X2E + i] = bx2e[i];
  for (int i = tid; i < 100; i += 64) w[W_ST + i]  = Wst[i];
  for (int i = tid; i < 10;  i += 64) w[B_ST + i]  = bst[i];
  if (tid < XD) xl[tid] = x[(size_t)(b * 65 + t) * XD + tid];
  __syncthreads();

  // h1a = elu(xa @ Wm1a^T + b)
  for (int c = tid; c < NAG * 8; c += 64) {
    int i = c >> 3, o = c & 7;
    float s = w[B_M1A + o];
#pragma unroll
    for (int f = 0; f < 4; f++) s += xl[i * 4 + f] * w[W_M1A + o * 4 + f];
    h1a[c] = elu_f(s);
  }
  __syncthreads();
  // h1 = elu(h1a @ Wm1b^T + b)
  for (int c = tid; c < NAG * 8; c += 64) {
    int i = c >> 3, o = c & 7;
    float s = w[B_M1B + o];
#pragma unroll
    for (int p = 0; p < 8; p++) s += h1a[i * 8 + p] * w[W_M1B + o * 8 + p];
    h1s[c] = elu_f(s);
  }
  __syncthreads();
  // h2a = elu(edges @ Wm2a^T + b)  (edge e: recv=e/9, send=q+(q>=r))
  for (int c = tid; c < NEDGE * 8; c += 64) {
    int e = c >> 3, o = c & 7;
    int r = e / 9, q = e - 9 * r;
    int sd = q + (q >= r ? 1 : 0);
    float s = w[B_M2A + o];
#pragma unroll
    for (int kk = 0; kk < 8; kk++) s += h1s[r * 8 + kk]  * w[W_M2A + o * 16 + kk];
#pragma unroll
    for (int kk = 0; kk < 8; kk++) s += h1s[sd * 8 + kk] * w[W_M2A + o * 16 + 8 + kk];
    h2a[c] = elu_f(s);
  }
  __syncthreads();

  bf16_t* Frow = F + (size_t)tok * KF;
  // gemb = elu(h2a @ Wm2b^T + b) -> F[43:763)
  for (int c = tid; c < NEDGE * 8; c += 64) {
    int e = c >> 3, o = c & 7;
    float s = w[B_M2B + o];
#pragma unroll
    for (int kk = 0; kk < 8; kk++) s += h2a[e * 8 + kk] * w[W_M2B + o * 8 + kk];
    Frow[43 + c] = (bf16_t)elu_f(s);
  }
  // xemb -> F[0:32)
  if (tid < 32) {
    float s = w[B_X2E + tid];
#pragma unroll
    for (int f = 0; f < 4; f++) s += xl[40 + f] * w[W_X2E + tid * 4 + f];
    Frow[tid] = (bf16_t)s;
  } else if (tid < 42) {               // demo -> F[32:42)
    int d = tid - 32;
    float s = w[B_ST + d];
#pragma unroll
    for (int j = 0; j < 10; j++) s += x_demo[b * XS + j] * w[W_ST + d * 10 + j];
    Frow[tid] = (bf16_t)s;
  } else if (tid == 42) {              // treat -> F[42]
    Frow[42] = (bf16_t)ftreat[b * 65 + t];
  } else if (tid < 48) {               // pad -> F[763:768) = 0
    Frow[720 + tid] = (bf16_t)0.f;
  }
}

// ---------------------------------------------------------------------------
// Kernel 3: G[16384,640] = F[16384,768] @ WT^T + bcat  (bf16 MFMA, fp32 acc)
// 128x128 block tile, 4 waves each 64x64, 16x16x32 bf16, BK=32
// ---------------------------------------------------------------------------
__global__ __launch_bounds__(256) void gemm_kernel(
    const bf16_t* __restrict__ F, const bf16_t* __restrict__ WT,
    const float* __restrict__ bcat, float* __restrict__ G) {
  __shared__ __align__(16) bf16_t As[128 * 32];
  __shared__ __align__(16) bf16_t Bs[128 * 32];

  int tid  = threadIdx.x;
  int lane = tid & 63;
  int wv   = tid >> 6;
  int wr   = wv >> 1, wc = wv & 1;
  int m0 = blockIdx.x * 128, n0 = blockIdx.y * 128;

  floatx4 acc[4][4];
#pragma unroll
  for (int i = 0; i < 4; i++)
#pragma unroll
    for (int j = 0; j < 4; j++) acc[i][j] = floatx4{0.f, 0.f, 0.f, 0.f};

  int c0 = tid, c1 = tid + 256;          // 16B chunks: row=c>>2, kp=c&3
  int r0 = c0 >> 2, p0 = c0 & 3;
  int r1 = c1 >> 2, p1 = c1 & 3;
  int qr = lane >> 4;                    // k-quad
  int lr = lane & 15;                    // m/n within tile

  for (int k0 = 0; k0 < KF; k0 += 32) {
    uint4 a0 = *(const uint4*)(F  + (size_t)(m0 + r0) * KF + k0 + p0 * 8);
    uint4 a1 = *(const uint4*)(F  + (size_t)(m0 + r1) * KF + k0 + p1 * 8);
    uint4 b0 = *(const uint4*)(WT + (size_t)(n0 + r0) * KF + k0 + p0 * 8);
    uint4 b1 = *(const uint4*)(WT + (size_t)(n0 + r1) * KF + k0 + p1 * 8);
    __syncthreads();
    ((uint4*)As)[c0] = a0; ((uint4*)As)[c1] = a1;
    ((uint4*)Bs)[c0] = b0; ((uint4*)Bs)[c1] = b1;
    __syncthreads();

    bf16x8 af[4], bf[4];
#pragma unroll
    for (int i = 0; i < 4; i++) {
      af[i] = *(const bf16x8*)(As + (wr * 64 + i * 16 + lr) * 32 + qr * 8);
      bf[i] = *(const bf16x8*)(Bs + (wc * 64 + i * 16 + lr) * 32 + qr * 8);
    }
#pragma unroll
    for (int i = 0; i < 4; i++)
#pragma unroll
      for (int j = 0; j < 4; j++)
        acc[i][j] = __builtin_amdgcn_mfma_f32_16x16x32_bf16(af[i], bf[j], acc[i][j], 0, 0, 0);
  }

  // epilogue: add bias, store fp32. C/D map: col=lane&15, row=(lane>>4)*4+reg
#pragma unroll
  for (int i = 0; i < 4; i++) {
#pragma unroll
    for (int j = 0; j < 4; j++) {
      int col = n0 + wc * 64 + j * 16 + lr;
      float bv = bcat[col];
#pragma unroll
      for (int r = 0; r < 4; r++) {
        int row = m0 + wr * 64 + i * 16 + qr * 4 + r;
        G[(size_t)row * NTOT + col] = acc[i][j][r] + bv;
      }
    }
  }
}

// ---------------------------------------------------------------------------
// Kernel 4: heads — a_out / y_out (one wave per token)
// ---------------------------------------------------------------------------
__global__ __launch_bounds__(256) void head_kernel(
    const float* __restrict__ G, const float* __restrict__ Wa2,
    const float* __restrict__ Wo2, float* __restrict__ out) {
  int wid  = (blockIdx.x * 256 + threadIdx.x) >> 6;   // token
  int lane = threadIdx.x & 63;
  const float* g = G + (size_t)wid * NTOT;
  float sa = fmaxf(g[lane], 0.f) * Wa2[lane] + fmaxf(g[lane + 64], 0.f) * Wa2[lane + 64];
  float sy = fmaxf(g[128 + lane], 0.f) * Wo2[lane] + fmaxf(g[192 + lane], 0.f) * Wo2[lane + 64];
#pragma unroll
  for (int off = 32; off > 0; off >>= 1) {
    sa += __shfl_down(sa, off, 64);
    sy += __shfl_down(sy, off, 64);
  }
  if (lane == 0) {
    out[(size_t)wid * 130 + 0] = sa;
    out[(size_t)wid * 130 + 1] = sy;
  }
}

// ---------------------------------------------------------------------------
// Kernel 5: GRU — one block per sequence, 512 threads:
//   waves 0-5 (tid<384): thread n owns W_hh row n in VGPRs, computes gh[n]
//   waves 6-7 (tid>=384, j=tid-384<128): hold gi(t) in regs, prefetch gi(t+1)
//     during the matvec phase, then do the gate math after the barrier.
// 2 barriers/step; global-load latency fully overlapped with the matvec.
// ---------------------------------------------------------------------------
__global__ __launch_bounds__(512, 2) void gru_kernel(
    const float* __restrict__ G, const float* __restrict__ h0,
    const float* __restrict__ Whh, const float* __restrict__ bhh,
    float* __restrict__ out) {
  int b = blockIdx.x;
  int tid = threadIdx.x;

  __shared__ float hbuf[2][HID];
  __shared__ float gh[384];

  bool is_mat = tid < 384;
  int j = tid - 384;
  const float* gbase = G + (size_t)b * TT * NTOT;

  float wrow[HID];
  float bias = 0.f;
  float ir = 0.f, iz = 0.f, inn = 0.f;
  if (is_mat) {
#pragma unroll
    for (int k = 0; k < HID; k += 4) {
      float4 v = *(const float4*)(Whh + (size_t)tid * HID + k);
      wrow[k] = v.x; wrow[k + 1] = v.y; wrow[k + 2] = v.z; wrow[k + 3] = v.w;
    }
    bias = bhh[tid];
  } else {
    ir  = gbase[256 + j];
    iz  = gbase[384 + j];
    inn = gbase[512 + j];
  }
  if (tid < HID) hbuf[0][tid] = h0[(size_t)b * HID + tid];
  __syncthreads();

  int cur = 0;
  for (int t = 0; t < TT; t++) {
    float nir = 0.f, niz = 0.f, ninn = 0.f;
    if (is_mat) {
      // 128-dot against broadcast h; 4 accumulators to shorten the dep chain
      float s0 = 0.f, s1 = 0.f, s2 = 0.f, s3 = 0.f;
#pragma unroll
      for (int k = 0; k < HID; k += 16) {
        float4 a = *(const float4*)(&hbuf[cur][k]);
        float4 c = *(const float4*)(&hbuf[cur][k + 4]);
        float4 d = *(const float4*)(&hbuf[cur][k + 8]);
        float4 e = *(const float4*)(&hbuf[cur][k + 12]);
        s0 += wrow[k] * a.x + wrow[k + 1] * a.y + wrow[k + 2] * a.z + wrow[k + 3] * a.w;
        s1 += wrow[k + 4] * c.x + wrow[k + 5] * c.y + wrow[k + 6] * c.z + wrow[k + 7] * c.w;
        s2 += wrow[k + 8] * d.x + wrow[k + 9] * d.y + wrow[k + 10] * d.z + wrow[k + 11] * d.w;
        s3 += wrow[k + 12] * e.x + wrow[k + 13] * e.y + wrow[k + 14] * e.z + wrow[k + 15] * e.w;
      }
      gh[tid] = (s0 + s1) + (s2 + s3) + bias;
    } else if (t + 1 < TT) {
      // prefetch next step's gi while waves 0-5 compute the matvec
      const float* gn = gbase + (size_t)(t + 1) * NTOT;
      nir  = gn[256 + j];
      niz  = gn[384 + j];
      ninn = gn[512 + j];
    }
    __syncthreads();
    if (!is_mat) {
      float r  = sigmoid_fast(ir + gh[j]);
      float z  = sigmoid_fast(iz + gh[128 + j]);
      float nn = tanh_fast(inn + r * gh[256 + j]);
      float hn = (1.f - z) * nn + z * hbuf[cur][j];
      hbuf[cur ^ 1][j] = hn;
      out[(size_t)(b * TT + t) * 130 + 2 + j] = hn;
      ir = nir; iz = niz; inn = ninn;
    }
    __syncthreads();
    cur ^= 1;
  }
}

// ---------------------------------------------------------------------------
extern "C" void kernel_launch(void* const* d_in, const int* in_sizes, int n_in,
                              void* d_out, int out_size, void* d_ws, size_t ws_size,
                              hipStream_t stream) {
  const float* x      = (const float*)d_in[0];
  const float* x_demo = (const float*)d_in[1];
  const float* ftr    = (const float*)d_in[2];
  const float* h0     = (const float*)d_in[3];
  const float* Wx2e   = (const float*)d_in[4];
  const float* bx2e   = (const float*)d_in[5];
  const float* Wst    = (const float*)d_in[6];
  const float* bst    = (const float*)d_in[7];
  const float* Wm1a   = (const float*)d_in[8];
  const float* bm1a   = (const float*)d_in[9];
  const float* Wm1b   = (const float*)d_in[10];
  const float* bm1b   = (const float*)d_in[11];
  const float* Wm2a   = (const float*)d_in[12];
  const float* bm2a   = (const float*)d_in[13];
  const float* Wm2b   = (const float*)d_in[14];
  const float* bm2b   = (const float*)d_in[15];
  const float* Wa1    = (const float*)d_in[16];
  const float* ba1    = (const float*)d_in[17];
  const float* Wa2    = (const float*)d_in[18];
  const float* Wo1    = (const float*)d_in[19];
  const float* bo1    = (const float*)d_in[20];
  const float* Wo2    = (const float*)d_in[21];
  const float* Wih    = (const float*)d_in[22];
  const float* bih    = (const float*)d_in[23];
  const float* Whh    = (const float*)d_in[24];
  const float* bhh    = (const float*)d_in[25];
  float* out = (float*)d_out;

  char* ws = (char*)d_ws;
  bf16_t* F   = (bf16_t*)(ws);                             // 16384*768*2 = 25165824
  bf16_t* WT  = (bf16_t*)(ws + 25165824);                  // 640*768*2   = 983040
  float*  bc  = (float*)(ws + 25165824 + 983040);          // 640*4       = 2560
  float*  G   = (float*)(ws + 25165824 + 983040 + 2560);   // 16384*640*4 = 41943040

  prep_kernel<<<dim3((NTOT * KF + 255) / 256), dim3(256), 0, stream>>>(
      Wa1, ba1, Wo1, bo1, Wih, bih, WT, bc);
  encoder_kernel<<<dim3(BT), dim3(64), 0, stream>>>(
      x, x_demo, ftr, Wm1a, bm1a, Wm1b, bm1b, Wm2a, bm2a, Wm2b, bm2b,
      Wx2e, bx2e, Wst, bst, F);
  gemm_kernel<<<dim3(BT / 128, NTOT / 128), dim3(256), 0, stream>>>(F, WT, bc, G);
  head_kernel<<<dim3(BT / 4), dim3(256), 0, stream>>>(G, Wa2, Wo2, out);
  gru_kernel<<<dim3(BB), dim3(512), 0, stream>>>(G, h0, Whh, bhh, out);
}

// Round 3
// 242.693 us; speedup vs baseline: 1.1541x; 1.0863x over previous
//
#include <hip/hip_runtime.h>
#include <hip/hip_bf16.h>
#include <math.h>

// ---- problem constants ----
#define BB     256
#define TT     64
#define BT     (BB*TT)      // 16384 tokens
#define XD     44
#define XP     40
#define XS     10
#define HID    128
#define XEMB   32
#define NHID   8
#define NAG    10
#define NEDGE  90
#define GEMB   720          // NHID*NEDGE
#define KF     768          // padded fused feature dim (763 -> 768)
#define NTOT   640          // 128 (a) + 128 (o) + 384 (ih)

typedef __bf16  bf16_t;
typedef __bf16  bf16x8 __attribute__((ext_vector_type(8)));
typedef float   floatx4 __attribute__((ext_vector_type(4)));
typedef _Float16 half2_t __attribute__((ext_vector_type(2)));

__device__ __forceinline__ float elu_f(float v) { return v > 0.f ? v : expm1f(v); }
__device__ __forceinline__ float rcp_fast(float x) { return __builtin_amdgcn_rcpf(x); }
__device__ __forceinline__ float sigmoid_fast(float v) { return rcp_fast(1.f + __expf(-v)); }
// inf-safe fast tanh: x->+inf => 1, x->-inf => -1
__device__ __forceinline__ float tanh_fast(float x) { return 1.f - 2.f * rcp_fast(1.f + __expf(2.f * x)); }

// ---------------------------------------------------------------------------
// Kernel 1: build Wcat^T (n-major, k-contiguous) bf16 + fused bias (fp32)
// F feature layout: [0:32) xemb | [32:42) demo | [42] treat | [43:763) gemb | [763:768) pad0
// ---------------------------------------------------------------------------
__global__ __launch_bounds__(256) void prep_kernel(
    const float* __restrict__ Wa1, const float* __restrict__ ba1,
    const float* __restrict__ Wo1, const float* __restrict__ bo1,
    const float* __restrict__ Wih, const float* __restrict__ bih,
    bf16_t* __restrict__ WT, float* __restrict__ bcat) {
  int idx = blockIdx.x * 256 + threadIdx.x;
  if (idx >= NTOT * KF) return;
  int n = idx / KF, k = idx - n * KF;
  float v = 0.f;
  if (n < 128) {                       // W_a1: a_in = [demo(10), gemb(720)]
    if (k >= 32 && k < 42)        v = Wa1[n * 730 + (k - 32)];
    else if (k >= 43 && k < 763)  v = Wa1[n * 730 + 10 + (k - 43)];
  } else if (n < 256) {                // W_o1: o_in == F[0:763] exactly
    int m = n - 128;
    if (k < 763)                  v = Wo1[m * 763 + k];
  } else {                             // W_ih: rnn_in = [xemb(32), treat(1), gemb(720)]
    int m = n - 256;
    if (k < 32)                   v = Wih[m * 753 + k];
    else if (k == 42)             v = Wih[m * 753 + 32];
    else if (k >= 43 && k < 763)  v = Wih[m * 753 + 33 + (k - 43)];
  }
  WT[n * KF + k] = (bf16_t)v;
  if (k == 0) {
    bcat[n] = (n < 128) ? ba1[n] : (n < 256 ? bo1[n - 128] : bih[n - 256]);
  }
}

// ---------------------------------------------------------------------------
// Kernel 2: per-token graph-net encoder -> F (bf16, 16384 x 768)
// one wave (64 threads) per token
// ---------------------------------------------------------------------------
#define W_M1A 0
#define B_M1A 32
#define W_M1B 40
#define B_M1B 104
#define W_M2A 112
#define B_M2A 240
#define W_M2B 248
#define B_M2B 312
#define W_X2E 320
#define B_X2E 448
#define W_ST  480
#define B_ST  580
#define W_TOT 590

__global__ __launch_bounds__(64) void encoder_kernel(
    const float* __restrict__ x, const float* __restrict__ x_demo,
    const float* __restrict__ ftreat,
    const float* __restrict__ Wm1a, const float* __restrict__ bm1a,
    const float* __restrict__ Wm1b, const float* __restrict__ bm1b,
    const float* __restrict__ Wm2a, const float* __restrict__ bm2a,
    const float* __restrict__ Wm2b, const float* __restrict__ bm2b,
    const float* __restrict__ Wx2e, const float* __restrict__ bx2e,
    const float* __restrict__ Wst, const float* __restrict__ bst,
    bf16_t* __restrict__ F) {
  int tok = blockIdx.x;
  int b = tok >> 6, t = tok & 63;
  int tid = threadIdx.x;

  __shared__ float w[W_TOT];
  __shared__ float xl[XD];
  __shared__ float h1a[NAG * 8];
  __shared__ float h1s[NAG * 8];
  __shared__ float h2a[NEDGE * 8];

  for (int i = tid; i < 32;  i += 64) w[W_M1A + i] = Wm1a[i];
  for (int i = tid; i < 8;   i += 64) w[B_M1A + i] = bm1a[i];
  for (int i = tid; i < 64;  i += 64) w[W_M1B + i] = Wm1b[i];
  for (int i = tid; i < 8;   i += 64) w[B_M1B + i] = bm1b[i];
  for (int i = tid; i < 128; i += 64) w[W_M2A + i] = Wm2a[i];
  for (int i = tid; i < 8;   i += 64) w[B_M2A + i] = bm2a[i];
  for (int i = tid; i < 64;  i += 64) w[W_M2B + i] = Wm2b[i];
  for (int i = tid; i < 8;   i += 64) w[B_M2B + i] = bm2b[i];
  for (int i = tid; i < 128; i += 64) w[W_X2E + i] = Wx2e[i];
  for (int i = tid; i < 32;  i += 64) w[B_X2E + i] = bx2e[i];
  for (int i = tid; i < 100; i += 64) w[W_ST + i]  = Wst[i];
  for (int i = tid; i < 10;  i += 64) w[B_ST + i]  = bst[i];
  if (tid < XD) xl[tid] = x[(size_t)(b * 65 + t) * XD + tid];
  __syncthreads();

  // h1a = elu(xa @ Wm1a^T + b)
  for (int c = tid; c < NAG * 8; c += 64) {
    int i = c >> 3, o = c & 7;
    float s = w[B_M1A + o];
#pragma unroll
    for (int f = 0; f < 4; f++) s += xl[i * 4 + f] * w[W_M1A + o * 4 + f];
    h1a[c] = elu_f(s);
  }
  __syncthreads();
  // h1 = elu(h1a @ Wm1b^T + b)
  for (int c = tid; c < NAG * 8; c += 64) {
    int i = c >> 3, o = c & 7;
    float s = w[B_M1B + o];
#pragma unroll
    for (int p = 0; p < 8; p++) s += h1a[i * 8 + p] * w[W_M1B + o * 8 + p];
    h1s[c] = elu_f(s);
  }
  __syncthreads();
  // h2a = elu(edges @ Wm2a^T + b)  (edge e: recv=e/9, send=q+(q>=r))
  for (int c = tid; c < NEDGE * 8; c += 64) {
    int e = c >> 3, o = c & 7;
    int r = e / 9, q = e - 9 * r;
    int sd = q + (q >= r ? 1 : 0);
    float s = w[B_M2A + o];
#pragma unroll
    for (int kk = 0; kk < 8; kk++) s += h1s[r * 8 + kk]  * w[W_M2A + o * 16 + kk];
#pragma unroll
    for (int kk = 0; kk < 8; kk++) s += h1s[sd * 8 + kk] * w[W_M2A + o * 16 + 8 + kk];
    h2a[c] = elu_f(s);
  }
  __syncthreads();

  bf16_t* Frow = F + (size_t)tok * KF;
  // gemb = elu(h2a @ Wm2b^T + b) -> F[43:763)
  for (int c = tid; c < NEDGE * 8; c += 64) {
    int e = c >> 3, o = c & 7;
    float s = w[B_M2B + o];
#pragma unroll
    for (int kk = 0; kk < 8; kk++) s += h2a[e * 8 + kk] * w[W_M2B + o * 8 + kk];
    Frow[43 + c] = (bf16_t)elu_f(s);
  }
  // xemb -> F[0:32)
  if (tid < 32) {
    float s = w[B_X2E + tid];
#pragma unroll
    for (int f = 0; f < 4; f++) s += xl[40 + f] * w[W_X2E + tid * 4 + f];
    Frow[tid] = (bf16_t)s;
  } else if (tid < 42) {               // demo -> F[32:42)
    int d = tid - 32;
    float s = w[B_ST + d];
#pragma unroll
    for (int j = 0; j < 10; j++) s += x_demo[b * XS + j] * w[W_ST + d * 10 + j];
    Frow[tid] = (bf16_t)s;
  } else if (tid == 42) {              // treat -> F[42]
    Frow[42] = (bf16_t)ftreat[b * 65 + t];
  } else if (tid < 48) {               // pad -> F[763:768) = 0
    Frow[720 + tid] = (bf16_t)0.f;
  }
}

// ---------------------------------------------------------------------------
// Kernel 3: G[16384,640] = F[16384,768] @ WT^T + bcat  (bf16 MFMA, fp32 acc)
// 128x128 block tile, 4 waves each 64x64, 16x16x32 bf16, BK=32
// ---------------------------------------------------------------------------
__global__ __launch_bounds__(256) void gemm_kernel(
    const bf16_t* __restrict__ F, const bf16_t* __restrict__ WT,
    const float* __restrict__ bcat, float* __restrict__ G) {
  __shared__ __align__(16) bf16_t As[128 * 32];
  __shared__ __align__(16) bf16_t Bs[128 * 32];

  int tid  = threadIdx.x;
  int lane = tid & 63;
  int wv   = tid >> 6;
  int wr   = wv >> 1, wc = wv & 1;
  int m0 = blockIdx.x * 128, n0 = blockIdx.y * 128;

  floatx4 acc[4][4];
#pragma unroll
  for (int i = 0; i < 4; i++)
#pragma unroll
    for (int j = 0; j < 4; j++) acc[i][j] = floatx4{0.f, 0.f, 0.f, 0.f};

  int c0 = tid, c1 = tid + 256;          // 16B chunks: row=c>>2, kp=c&3
  int r0 = c0 >> 2, p0 = c0 & 3;
  int r1 = c1 >> 2, p1 = c1 & 3;
  int qr = lane >> 4;                    // k-quad
  int lr = lane & 15;                    // m/n within tile

  for (int k0 = 0; k0 < KF; k0 += 32) {
    uint4 a0 = *(const uint4*)(F  + (size_t)(m0 + r0) * KF + k0 + p0 * 8);
    uint4 a1 = *(const uint4*)(F  + (size_t)(m0 + r1) * KF + k0 + p1 * 8);
    uint4 b0 = *(const uint4*)(WT + (size_t)(n0 + r0) * KF + k0 + p0 * 8);
    uint4 b1 = *(const uint4*)(WT + (size_t)(n0 + r1) * KF + k0 + p1 * 8);
    __syncthreads();
    ((uint4*)As)[c0] = a0; ((uint4*)As)[c1] = a1;
    ((uint4*)Bs)[c0] = b0; ((uint4*)Bs)[c1] = b1;
    __syncthreads();

    bf16x8 af[4], bf[4];
#pragma unroll
    for (int i = 0; i < 4; i++) {
      af[i] = *(const bf16x8*)(As + (wr * 64 + i * 16 + lr) * 32 + qr * 8);
      bf[i] = *(const bf16x8*)(Bs + (wc * 64 + i * 16 + lr) * 32 + qr * 8);
    }
#pragma unroll
    for (int i = 0; i < 4; i++)
#pragma unroll
      for (int j = 0; j < 4; j++)
        acc[i][j] = __builtin_amdgcn_mfma_f32_16x16x32_bf16(af[i], bf[j], acc[i][j], 0, 0, 0);
  }

  // epilogue: add bias, store fp32. C/D map: col=lane&15, row=(lane>>4)*4+reg
#pragma unroll
  for (int i = 0; i < 4; i++) {
#pragma unroll
    for (int j = 0; j < 4; j++) {
      int col = n0 + wc * 64 + j * 16 + lr;
      float bv = bcat[col];
#pragma unroll
      for (int r = 0; r < 4; r++) {
        int row = m0 + wr * 64 + i * 16 + qr * 4 + r;
        G[(size_t)row * NTOT + col] = acc[i][j][r] + bv;
      }
    }
  }
}

// ---------------------------------------------------------------------------
// Kernel 4: heads — a_out / y_out (one wave per token)
// ---------------------------------------------------------------------------
__global__ __launch_bounds__(256) void head_kernel(
    const float* __restrict__ G, const float* __restrict__ Wa2,
    const float* __restrict__ Wo2, float* __restrict__ out) {
  int wid  = (blockIdx.x * 256 + threadIdx.x) >> 6;   // token
  int lane = threadIdx.x & 63;
  const float* g = G + (size_t)wid * NTOT;
  float sa = fmaxf(g[lane], 0.f) * Wa2[lane] + fmaxf(g[lane + 64], 0.f) * Wa2[lane + 64];
  float sy = fmaxf(g[128 + lane], 0.f) * Wo2[lane] + fmaxf(g[192 + lane], 0.f) * Wo2[lane + 64];
#pragma unroll
  for (int off = 32; off > 0; off >>= 1) {
    sa += __shfl_down(sa, off, 64);
    sy += __shfl_down(sy, off, 64);
  }
  if (lane == 0) {
    out[(size_t)wid * 130 + 0] = sa;
    out[(size_t)wid * 130 + 1] = sy;
  }
}

// ---------------------------------------------------------------------------
// Kernel 5: GRU — one block per sequence, 384 threads (6 waves).
// Matvec: thread n owns W_hh row n as 64 packed half2 VGPRs. h is broadcast
// via v_readlane from ONE ds_read_b32 per wave (packed half2 in LDS) —
// no per-thread LDS broadcast traffic (R1's 192 ds_read_b128/step -> 6 b32).
// Dot via v_dot2_f32_f16 (f32 accumulate). Gate threads (tid<128) also
// prefetch gi(t+1) during the matvec. 2 barriers/step.
// ---------------------------------------------------------------------------
__global__ __launch_bounds__(384, 1) void gru_kernel(
    const float* __restrict__ G, const float* __restrict__ h0,
    const float* __restrict__ Whh, const float* __restrict__ bhh,
    float* __restrict__ out) {
  int b = blockIdx.x;
  int tid = threadIdx.x;          // 0..383
  int lane = tid & 63;
  bool gate = tid < HID;

  __shared__ float gh[384];
  __shared__ unsigned int h2[HID / 2];   // packed half2: (h[2l], h[2l+1])

  const float* gbase = G + (size_t)b * TT * NTOT;

  // W_hh row tid -> 64 packed half2 in VGPRs
  half2_t w2[64];
#pragma unroll
  for (int k = 0; k < HID; k += 4) {
    float4 v = *(const float4*)(Whh + (size_t)tid * HID + k);
    w2[k / 2]     = half2_t{(_Float16)v.x, (_Float16)v.y};
    w2[k / 2 + 1] = half2_t{(_Float16)v.z, (_Float16)v.w};
  }
  float bias = bhh[tid];

  float hprev = 0.f, ir = 0.f, iz = 0.f, inn = 0.f;
  if (gate) {
    hprev = h0[(size_t)b * HID + tid];
    ((_Float16*)h2)[tid] = (_Float16)hprev;
    ir  = gbase[256 + tid];
    iz  = gbase[384 + tid];
    inn = gbase[512 + tid];
  }
  __syncthreads();

  for (int t = 0; t < TT; t++) {
    unsigned int hl = h2[lane];        // one b32/lane: packed (h[2l],h[2l+1])
    float nir = 0.f, niz = 0.f, ninn = 0.f;
    if (gate && t + 1 < TT) {          // prefetch overlaps the matvec
      const float* gn = gbase + (size_t)(t + 1) * NTOT;
      nir  = gn[256 + tid];
      niz  = gn[384 + tid];
      ninn = gn[512 + tid];
    }
    float s0 = 0.f, s1 = 0.f;
#pragma unroll
    for (int k = 0; k < 64; k += 2) {
      int p0 = __builtin_amdgcn_readlane((int)hl, k);
      int p1 = __builtin_amdgcn_readlane((int)hl, k + 1);
      s0 = __builtin_amdgcn_fdot2(w2[k],     __builtin_bit_cast(half2_t, p0), s0, false);
      s1 = __builtin_amdgcn_fdot2(w2[k + 1], __builtin_bit_cast(half2_t, p1), s1, false);
    }
    gh[tid] = s0 + s1 + bias;
    __syncthreads();
    if (gate) {
      float r  = sigmoid_fast(ir + gh[tid]);
      float z  = sigmoid_fast(iz + gh[HID + tid]);
      float nn = tanh_fast(inn + r * gh[2 * HID + tid]);
      float hn = (1.f - z) * nn + z * hprev;
      hprev = hn;
      out[(size_t)(b * TT + t) * 130 + 2 + tid] = hn;
      ((_Float16*)h2)[tid] = (_Float16)hn;
      ir = nir; iz = niz; inn = ninn;
    }
    __syncthreads();
  }
}

// ---------------------------------------------------------------------------
extern "C" void kernel_launch(void* const* d_in, const int* in_sizes, int n_in,
                              void* d_out, int out_size, void* d_ws, size_t ws_size,
                              hipStream_t stream) {
  const float* x      = (const float*)d_in[0];
  const float* x_demo = (const float*)d_in[1];
  const float* ftr    = (const float*)d_in[2];
  const float* h0     = (const float*)d_in[3];
  const float* Wx2e   = (const float*)d_in[4];
  const float* bx2e   = (const float*)d_in[5];
  const float* Wst    = (const float*)d_in[6];
  const float* bst    = (const float*)d_in[7];
  const float* Wm1a   = (const float*)d_in[8];
  const float* bm1a   = (const float*)d_in[9];
  const float* Wm1b   = (const float*)d_in[10];
  const float* bm1b   = (const float*)d_in[11];
  const float* Wm2a   = (const float*)d_in[12];
  const float* bm2a   = (const float*)d_in[13];
  const float* Wm2b   = (const float*)d_in[14];
  const float* bm2b   = (const float*)d_in[15];
  const float* Wa1    = (const float*)d_in[16];
  const float* ba1    = (const float*)d_in[17];
  const float* Wa2    = (const float*)d_in[18];
  const float* Wo1    = (const float*)d_in[19];
  const float* bo1    = (const float*)d_in[20];
  const float* Wo2    = (const float*)d_in[21];
  const float* Wih    = (const float*)d_in[22];
  const float* bih    = (const float*)d_in[23];
  const float* Whh    = (const float*)d_in[24];
  const float* bhh    = (const float*)d_in[25];
  float* out = (float*)d_out;

  char* ws = (char*)d_ws;
  bf16_t* F   = (bf16_t*)(ws);                             // 16384*768*2 = 25165824
  bf16_t* WT  = (bf16_t*)(ws + 25165824);                  // 640*768*2   = 983040
  float*  bc  = (float*)(ws + 25165824 + 983040);          // 640*4       = 2560
  float*  G   = (float*)(ws + 25165824 + 983040 + 2560);   // 16384*640*4 = 41943040

  prep_kernel<<<dim3((NTOT * KF + 255) / 256), dim3(256), 0, stream>>>(
      Wa1, ba1, Wo1, bo1, Wih, bih, WT, bc);
  encoder_kernel<<<dim3(BT), dim3(64), 0, stream>>>(
      x, x_demo, ftr, Wm1a, bm1a, Wm1b, bm1b, Wm2a, bm2a, Wm2b, bm2b,
      Wx2e, bx2e, Wst, bst, F);
  gemm_kernel<<<dim3(BT / 128, NTOT / 128), dim3(256), 0, stream>>>(F, WT, bc, G);
  head_kernel<<<dim3(BT / 4), dim3(256), 0, stream>>>(G, Wa2, Wo2, out);
  gru_kernel<<<dim3(BB), dim3(384), 0, stream>>>(G, h0, Whh, bhh, out);
}